// Round 6
// baseline (170.282 us; speedup 1.0000x reference)
//
#include <hip/hip_runtime.h>

#define B_ 16
#define T_ 12
#define N_ 512
#define D_ 128
#define E_ 32

typedef __attribute__((ext_vector_type(8))) unsigned short u16x8;
typedef __attribute__((ext_vector_type(8))) __bf16 bf16x8;
typedef __attribute__((ext_vector_type(4))) float f32x4;

static __device__ __forceinline__ unsigned short f2bf(float f) {
    unsigned u = __float_as_uint(f);
    unsigned r = (u + 0x7fffu + ((u >> 16) & 1u)) >> 16;
    return (unsigned short)r;
}

// ---------------------------------------------------------------------------
// kP1: three independent parts in one launch (256 thr):
//  blocks [0,1536):    qk+row-softmax, wave-per-row (4 rows/block, no barriers)
//                      writes qkf (fp32) and qb (bf16)
//  blocks [1536,2048): kM: pack mask bits
//  blocks [2048,2112): kW: WvT[d][k] = bf16(Wv[k][d])
// ---------------------------------------------------------------------------
__global__ __launch_bounds__(256) void kP1(const float* __restrict__ emb,
                                           const float* __restrict__ Wqk,
                                           const float* __restrict__ bqk,
                                           float* __restrict__ qk,
                                           unsigned short* __restrict__ qb,
                                           const int* __restrict__ mask,
                                           unsigned* __restrict__ mb,
                                           const float* __restrict__ Wv,
                                           unsigned short* __restrict__ WvT) {
    int bid = blockIdx.x;
    int tid = threadIdx.x;
    if (bid >= 2048) {  // ---- kW ----
        int i = (bid - 2048) * 256 + tid;  // 0..16383
        int d = i >> 7, k = i & 127;
        WvT[d * 128 + k] = f2bf(Wv[k * 128 + d]);
        return;
    }
    if (bid >= 1536) {  // ---- kM ----
        int o = (bid - 1536) * 256 + tid;  // 0..131071
        const int* mp = mask + (size_t)o * 32;
        unsigned bits = 0;
#pragma unroll
        for (int j = 0; j < 32; j += 4) {
            int4 m4 = *(const int4*)&mp[j];
            bits |= (m4.x ? 1u : 0u) << j;
            bits |= (m4.y ? 1u : 0u) << (j + 1);
            bits |= (m4.z ? 1u : 0u) << (j + 2);
            bits |= (m4.w ? 1u : 0u) << (j + 3);
        }
        mb[o] = bits;
        return;
    }
    // ---- qk + row softmax, one wave per (t,n) row ----
    int wave = tid >> 6, lane = tid & 63;
    int tn = bid * 4 + wave;  // 0..6143
    const float* er = emb + (size_t)tn * E_;
    float a0 = bqk[lane], a1 = bqk[lane + 64];
#pragma unroll
    for (int e = 0; e < E_; ++e) {
        float ev = er[e];
        a0 = fmaf(ev, Wqk[e * D_ + lane], a0);
        a1 = fmaf(ev, Wqk[e * D_ + lane + 64], a1);
    }
    float* qr = qk + (size_t)tn * D_;
    qr[lane] = a0;
    qr[lane + 64] = a1;
    float mx = fmaxf(a0, a1);
#pragma unroll
    for (int s = 32; s > 0; s >>= 1) mx = fmaxf(mx, __shfl_xor(mx, s, 64));
    float e0 = __expf(a0 - mx), e1 = __expf(a1 - mx);
    float sum = e0 + e1;
#pragma unroll
    for (int s = 32; s > 0; s >>= 1) sum += __shfl_xor(sum, s, 64);
    float inv = 1.f / sum;
    unsigned short* qo = qb + (size_t)tn * D_;
    qo[lane] = f2bf(e0 * inv);
    qo[lane + 64] = f2bf(e1 * inv);
}

// ---------------------------------------------------------------------------
// kA2n: kN[t,n,d] = softmax over n of qk[t,n,d], kept [n][d], bf16.
// grid (t=12 x dtile=32) = 384 blocks; 256 thr = 64(ni) x 4(dc); 8 n/thread.
// wave covers 16 rows x 16 contiguous bytes.
// ---------------------------------------------------------------------------
__global__ __launch_bounds__(256) void kA2n(const float* __restrict__ qk,
                                            unsigned short* __restrict__ kN) {
    int t = blockIdx.x >> 5;
    int d0 = (blockIdx.x & 31) * 4;
    int tid = threadIdx.x;
    int dc = tid & 3, ni = tid >> 2;  // ni 0..63
    const float* base = qk + (size_t)t * N_ * D_ + d0 + dc;
    float vals[8];
    float mx = -1e30f;
#pragma unroll
    for (int j = 0; j < 8; ++j) {
        vals[j] = base[(size_t)(ni + 64 * j) * D_];
        mx = fmaxf(mx, vals[j]);
    }
    __shared__ float red[64][5];
    red[ni][dc] = mx;
    __syncthreads();
#pragma unroll
    for (int s = 32; s > 0; s >>= 1) {
        if (ni < s) red[ni][dc] = fmaxf(red[ni][dc], red[ni + s][dc]);
        __syncthreads();
    }
    mx = red[0][dc];
    float sum = 0.f;
#pragma unroll
    for (int j = 0; j < 8; ++j) {
        vals[j] = __expf(vals[j] - mx);
        sum += vals[j];
    }
    __syncthreads();
    red[ni][dc] = sum;
    __syncthreads();
#pragma unroll
    for (int s = 32; s > 0; s >>= 1) {
        if (ni < s) red[ni][dc] += red[ni + s][dc];
        __syncthreads();
    }
    float inv = 1.f / red[0][dc];
    unsigned short* op = kN + (size_t)t * N_ * D_ + d0 + dc;
#pragma unroll
    for (int j = 0; j < 8; ++j)
        op[(size_t)(ni + 64 * j) * D_] = f2bf(vals[j] * inv);
}

// ---------------------------------------------------------------------------
// kF: fused MFMA mid-stage. 256 thr.
//  blocks [0,192):   A3m: sc[t,n,m] = qb @ kN^T (bf16 MFMA, 128x128 tile)
//  blocks [192,960): Bm:  vT[bt][d][m] = WvT @ value^T + bv (bf16 MFMA)
// ---------------------------------------------------------------------------
__global__ __launch_bounds__(256) void kF(const unsigned short* __restrict__ qb,
                                          const unsigned short* __restrict__ kN,
                                          unsigned short* __restrict__ sc,
                                          const float* __restrict__ value,
                                          const unsigned short* __restrict__ WvT,
                                          const float* __restrict__ bv,
                                          unsigned short* __restrict__ vT) {
    __shared__ unsigned short shl[2][128 * 72];
    int bid = blockIdx.x;
    int tid = threadIdx.x;

    int wave = tid >> 6, lane = tid & 63;
    int q = lane >> 4, lr = lane & 15;
    int rbase = (wave & 1) * 64, cbase = (wave >> 1) * 64;

    f32x4 acc[4][4];
#pragma unroll
    for (int i = 0; i < 4; ++i)
#pragma unroll
        for (int j = 0; j < 4; ++j) acc[i][j] = (f32x4){0.f, 0.f, 0.f, 0.f};

    if (bid < 192) {  // ---- kA3m ----
        int mt = bid & 3, nt = (bid >> 2) & 3, t = bid >> 4;
        int n0 = nt * 128, m0 = mt * 128;
        unsigned short* Qs = shl[0];
        unsigned short* Ks = shl[1];
        const unsigned short* qp = qb + (size_t)t * N_ * D_ + (size_t)n0 * D_;
        const unsigned short* kp = kN + (size_t)t * N_ * D_ + (size_t)m0 * D_;

        for (int c = 0; c < 2; ++c) {
            int k0 = c * 64;
            __syncthreads();
#pragma unroll
            for (int i = 0; i < 4; ++i) {
                int lin = tid + i * 256;
                int r = lin >> 3, seg = lin & 7;
                *(u16x8*)&Qs[r * 72 + seg * 8] =
                    *(const u16x8*)&qp[(size_t)r * D_ + k0 + seg * 8];
                *(u16x8*)&Ks[r * 72 + seg * 8] =
                    *(const u16x8*)&kp[(size_t)r * D_ + k0 + seg * 8];
            }
            __syncthreads();
#pragma unroll
            for (int kk = 0; kk < 2; ++kk) {
                bf16x8 a[4], b[4];
#pragma unroll
                for (int i = 0; i < 4; ++i)
                    a[i] = *(const bf16x8*)&Qs[(rbase + 16 * i + lr) * 72 + kk * 32 + q * 8];
#pragma unroll
                for (int j = 0; j < 4; ++j)
                    b[j] = *(const bf16x8*)&Ks[(cbase + 16 * j + lr) * 72 + kk * 32 + q * 8];
#pragma unroll
                for (int i = 0; i < 4; ++i)
#pragma unroll
                    for (int j = 0; j < 4; ++j)
                        acc[i][j] = __builtin_amdgcn_mfma_f32_16x16x32_bf16(
                            a[i], b[j], acc[i][j], 0, 0, 0);
            }
        }
        unsigned short* sp = sc + (size_t)t * N_ * N_;
#pragma unroll
        for (int i = 0; i < 4; ++i)
#pragma unroll
            for (int j = 0; j < 4; ++j) {
                int row0 = n0 + rbase + 16 * i + q * 4;
                int col = m0 + cbase + 16 * j + lr;
#pragma unroll
                for (int e = 0; e < 4; ++e)
                    sp[(size_t)(row0 + e) * N_ + col] = f2bf(acc[i][j][e]);
            }
        return;
    }

    // ---- kBm ----
    {
        int idx = bid - 192;
        int mt = idx & 3, bt = idx >> 2;
        int m0 = mt * 128;
        unsigned short* Ws = shl[0];
        unsigned short* Vs = shl[1];
        const float* vp = value + ((size_t)bt * N_ + m0) * D_;

        for (int c = 0; c < 2; ++c) {
            int k0 = c * 64;
            __syncthreads();
#pragma unroll
            for (int i = 0; i < 4; ++i) {
                int lin = tid + i * 256;
                int r = lin >> 3, seg = lin & 7;
                *(u16x8*)&Ws[r * 72 + seg * 8] =
                    *(const u16x8*)&WvT[r * 128 + k0 + seg * 8];
            }
#pragma unroll
            for (int i = 0; i < 8; ++i) {
                int lin = tid + i * 256;
                int r = lin >> 4, c4 = lin & 15;
                float4 f = *(const float4*)&vp[(size_t)r * D_ + k0 + c4 * 4];
                ushort4 o;
                o.x = f2bf(f.x); o.y = f2bf(f.y); o.z = f2bf(f.z); o.w = f2bf(f.w);
                *(ushort4*)&Vs[r * 72 + c4 * 4] = o;
            }
            __syncthreads();
#pragma unroll
            for (int kk = 0; kk < 2; ++kk) {
                bf16x8 a[4], b[4];
#pragma unroll
                for (int i = 0; i < 4; ++i)
                    a[i] = *(const bf16x8*)&Ws[(rbase + 16 * i + lr) * 72 + kk * 32 + q * 8];
#pragma unroll
                for (int j = 0; j < 4; ++j)
                    b[j] = *(const bf16x8*)&Vs[(cbase + 16 * j + lr) * 72 + kk * 32 + q * 8];
#pragma unroll
                for (int i = 0; i < 4; ++i)
#pragma unroll
                    for (int j = 0; j < 4; ++j)
                        acc[i][j] = __builtin_amdgcn_mfma_f32_16x16x32_bf16(
                            a[i], b[j], acc[i][j], 0, 0, 0);
            }
        }
        unsigned short* op = vT + (size_t)bt * N_ * D_;
#pragma unroll
        for (int i = 0; i < 4; ++i) {
            int row0 = rbase + 16 * i + q * 4;
#pragma unroll
            for (int j = 0; j < 4; ++j) {
                int col = m0 + cbase + 16 * j + lr;
#pragma unroll
                for (int e = 0; e < 4; ++e)
                    op[(size_t)(row0 + e) * N_ + col] = f2bf(acc[i][j][e] + bv[row0 + e]);
            }
        }
    }
}

// ---------------------------------------------------------------------------
// kC: out[b,t,n,d] = sum_m (mask ? score0 : -1e9) * v[b,t,m,d]  via bf16 MFMA
// tile 128(n) x 128(d), K=512 in 8 chunks of 64, register-prefetch pipeline.
// ---------------------------------------------------------------------------
__global__ __launch_bounds__(256) void kC(const unsigned short* __restrict__ sc,
                                          const unsigned* __restrict__ mb,
                                          const unsigned short* __restrict__ vT,
                                          float* __restrict__ out) {
    int n0 = blockIdx.x * 128;
    int t = blockIdx.y, b = blockIdx.z;
    int tid = threadIdx.x;
    int wave = tid >> 6, lane = tid & 63;
    int q = lane >> 4, lr = lane & 15;
    int rbase = (wave & 1) * 64, cbase = (wave >> 1) * 64;

    __shared__ unsigned short Ss[128 * 72];
    __shared__ unsigned short Vs[128 * 72];

    const unsigned short* scp = sc + (size_t)t * N_ * N_ + (size_t)n0 * N_;
    const unsigned short* vtp = vT + ((size_t)(b * T_ + t)) * N_ * D_;
    const unsigned* mbp = mb + ((size_t)b * N_ + n0) * 16;

    const unsigned short NEG = 0xCE6E;  // bf16(-1e9)

    f32x4 acc[4][4];
#pragma unroll
    for (int i = 0; i < 4; ++i)
#pragma unroll
        for (int j = 0; j < 4; ++j) acc[i][j] = (f32x4){0.f, 0.f, 0.f, 0.f};

    int sr = tid >> 1, sh2 = tid & 1;
    const unsigned short* sg = scp + (size_t)sr * N_ + sh2 * 32;
    const unsigned short* vg = vtp + (size_t)sr * N_ + sh2 * 32;
    const unsigned* mwp = mbp + sr * 16 + sh2;

    u16x8 sreg[4], vreg[4];
    unsigned mw;
#pragma unroll
    for (int p = 0; p < 4; ++p) {
        sreg[p] = *(const u16x8*)(sg + p * 8);
        vreg[p] = *(const u16x8*)(vg + p * 8);
    }
    mw = mwp[0];

    for (int kc = 0; kc < 8; ++kc) {
        if (kc) __syncthreads();
        unsigned short* Sd = &Ss[sr * 72 + sh2 * 32];
        unsigned short* Vd = &Vs[sr * 72 + sh2 * 32];
#pragma unroll
        for (int p = 0; p < 4; ++p) {
            unsigned bits = mw >> (p * 8);
            u16x8 o;
#pragma unroll
            for (int j = 0; j < 8; ++j)
                o[j] = ((bits >> j) & 1u) ? sreg[p][j] : NEG;
            *(u16x8*)(Sd + p * 8) = o;
            *(u16x8*)(Vd + p * 8) = vreg[p];
        }
        __syncthreads();
        if (kc < 7) {
            int off = (kc + 1) * 64;
#pragma unroll
            for (int p = 0; p < 4; ++p) {
                sreg[p] = *(const u16x8*)(sg + off + p * 8);
                vreg[p] = *(const u16x8*)(vg + off + p * 8);
            }
            mw = mwp[(kc + 1) * 2];
        }
#pragma unroll
        for (int ks = 0; ks < 2; ++ks) {
            bf16x8 a[4], bfr[4];
#pragma unroll
            for (int i = 0; i < 4; ++i)
                a[i] = *(const bf16x8*)&Ss[(rbase + 16 * i + lr) * 72 + ks * 32 + q * 8];
#pragma unroll
            for (int j = 0; j < 4; ++j)
                bfr[j] = *(const bf16x8*)&Vs[(cbase + 16 * j + lr) * 72 + ks * 32 + q * 8];
#pragma unroll
            for (int i = 0; i < 4; ++i)
#pragma unroll
                for (int j = 0; j < 4; ++j)
                    acc[i][j] = __builtin_amdgcn_mfma_f32_16x16x32_bf16(
                        a[i], bfr[j], acc[i][j], 0, 0, 0);
        }
    }

    float* ob = out + ((size_t)(b * T_ + t)) * N_ * D_;
#pragma unroll
    for (int i = 0; i < 4; ++i) {
#pragma unroll
        for (int j = 0; j < 4; ++j) {
            int row0 = n0 + rbase + 16 * i + q * 4;
            int col = cbase + 16 * j + lr;
#pragma unroll
            for (int e = 0; e < 4; ++e)
                ob[(size_t)(row0 + e) * D_ + col] = acc[i][j][e];
        }
    }
}

// ---------------------------------------------------------------------------
extern "C" void kernel_launch(void* const* d_in, const int* in_sizes, int n_in,
                              void* d_out, int out_size, void* d_ws, size_t ws_size,
                              hipStream_t stream) {
    const float* value = (const float*)d_in[0];
    const float* emb   = (const float*)d_in[1];
    const int*   mask  = (const int*)d_in[2];
    const float* Wqk   = (const float*)d_in[3];
    const float* bqk   = (const float*)d_in[4];
    const float* Wv    = (const float*)d_in[5];
    const float* bvv   = (const float*)d_in[6];
    float* out = (float*)d_out;

    float* ws = (float*)d_ws;
    float*          qkf  = ws;                                // 786432 f
    unsigned short* qb   = (unsigned short*)(ws + 786432);    // 786432 u16
    unsigned short* kNb  = (unsigned short*)(ws + 1179648);   // 786432 u16
    unsigned short* scb  = (unsigned short*)(ws + 1572864);   // 3145728 u16
    unsigned short* vtb  = (unsigned short*)(ws + 3145728);   // 12582912 u16
    unsigned short* WvTb = (unsigned short*)(ws + 9437184);   // 16384 u16
    unsigned*       mbp  = (unsigned*)(ws + 9445376);         // 131072 u32

    kP1<<<2112, 256, 0, stream>>>(emb, Wqk, bqk, qkf, qb, mask, mbp, Wv, WvTb);
    kA2n<<<384, 256, 0, stream>>>(qkf, kNb);
    kF<<<960, 256, 0, stream>>>(qb, kNb, scb, value, WvTb, bvv, vtb);
    kC<<<dim3(4, T_, B_), 256, 0, stream>>>(scb, mbp, vtb, out);
}